// Round 1
// baseline (339.251 us; speedup 1.0000x reference)
//
#include <hip/hip_runtime.h>
#include <hip/hip_bf16.h>

typedef __attribute__((ext_vector_type(8))) _Float16 half8;
typedef __attribute__((ext_vector_type(4))) float f32x4;

#define NEGF (-1e30f)
#define NINF (-3.0e38f)

constexpr int CB = 48, CS = 128, CW = 4, CK = 256;
constexpr int LDP = 264;  // padded ebuf row stride (elements): 528B, breaks 16-way bank conflict

// eT[b][k][kp] = exp(T[b][k][kp] * tag_mask[b][k][kp]), f16, same layout as T (kp contiguous)
__global__ void prep_eT_kernel(const float* __restrict__ T,
                               const float* __restrict__ tm,
                               _Float16* __restrict__ eT, int n) {
    int i = blockIdx.x * 256 + threadIdx.x;
    if (i < n) eT[i] = (_Float16)__expf(T[i] * tm[i]);
}

__global__ __launch_bounds__(256, 1)
void crf_scan_kernel(const float* __restrict__ logits,
                     const float* __restrict__ ham,
                     const _Float16* __restrict__ eT,
                     const float* __restrict__ tag_mask,
                     const int* __restrict__ text_mask,
                     float* __restrict__ out) {
    const int b = blockIdx.x;
    const int tid = (int)threadIdx.x;
    const int wv = tid >> 6;      // wave 0..3, handles k in [64*wv, 64*wv+64)
    const int lane = tid & 63;
    const int l16 = lane & 15;
    const int g4 = lane >> 4;     // 0..3 (K-group within MFMA frag)

    // ebuf rows 0..3 = ring slots (slot of alpha_i is i&3); rows 4..15 stay zero (padded M=16)
    __shared__ _Float16 ebuf[16 * LDP];
    __shared__ float ylds[CK][4];      // y[k][slot]
    __shared__ float ls[CS + 1];       // logsumexp_k of full[j]
    __shared__ float mrow[4], serow[4];
    __shared__ float redm[4], reds[4];
    __shared__ int len_s;

    for (int i = tid; i < 16 * LDP; i += 256) ebuf[i] = (_Float16)0.0f;
    if (tid == 0) len_s = 0;
    __syncthreads();
    // alpha[-1] = zeros row -> m = 0, ebuf = 1, sum = 256; lives in slot (-1)&3 = 3
    if (tid < CK) ebuf[3 * LDP + tid] = (_Float16)1.0f;
    if (tid < 4) {
        mrow[tid]  = (tid == 3) ? 0.0f : NEGF;
        serow[tid] = (tid == 3) ? 256.0f : 1.0f;
    }
    if (tid == 0) ls[0] = __logf(256.0f);   // logsumexp of zeros over K
    if (tid < CS) atomicAdd(&len_s, text_mask[b * CS + tid]);

    const float tm0 = tag_mask[(size_t)b * CK * CK + tid];  // tag_mask[b,0,k]

    // persistent eT B-fragments: B[kp][k] = eT[b][k][kp]; lane l: k = l%16 (+tile), kp = 8*(l/16)+j (+chunk)
    half8 bfr[8][4];
    const _Float16* eTb = eT + (size_t)b * CK * CK;
#pragma unroll
    for (int c = 0; c < 8; ++c)
#pragma unroll
        for (int t = 0; t < 4; ++t) {
            int k = wv * 64 + t * 16 + l16;
            bfr[c][t] = *(const half8*)(eTb + (size_t)k * CK + c * 32 + g4 * 8);
        }

    const float* lg_b = logits + (size_t)b * CS * CW * CK;
    const float* hc_b = ham    + (size_t)b * CS * CW * CK;

    __syncthreads();

    for (int j = 0; j < CS; ++j) {
        // prefetch emission for this step (used only in epilogue; latency hidden behind MFMA)
        float em[4];
#pragma unroll
        for (int w = 0; w < CW; ++w) {
            int idx = j * CW * CK + w * CK + tid;
            em[w] = (lg_b[idx] + hc_b[idx]) * tm0;
        }

        // A-fragments from LDS: A[row=slot][kp], rows 4..15 = 0
        half8 af[8];
#pragma unroll
        for (int c = 0; c < 8; ++c)
            af[c] = *(const half8*)(ebuf + l16 * LDP + c * 32 + g4 * 8);

        // y[slot][k] = sum_kp ebuf[slot][kp] * eT[k][kp]
        f32x4 acc[4];
#pragma unroll
        for (int t = 0; t < 4; ++t) {
            f32x4 a = {0.0f, 0.0f, 0.0f, 0.0f};
#pragma unroll
            for (int c = 0; c < 8; ++c)
                a = __builtin_amdgcn_mfma_f32_16x16x32_f16(af[c], bfr[c][t], a, 0, 0, 0);
            acc[t] = a;
        }
        // D layout: col = lane&15, row = (lane>>4)*4 + reg -> lanes 0..15 hold rows(=slots) 0..3
        if (lane < 16) {
#pragma unroll
            for (int t = 0; t < 4; ++t) {
                int k = wv * 64 + t * 16 + l16;
                *(f32x4*)(&ylds[k][0]) = acc[t];
            }
        }
        __syncthreads();

        // epilogue: thread handles k = tid
        f32x4 y = *(const f32x4*)(&ylds[tid][0]);
        float tv[4];
#pragma unroll
        for (int s = 0; s < 4; ++s) {
            int w = (j - 1 - s) & 3;   // width index stored in slot s at step j
            int i = j - 1 - w;         // alpha index (i == -1: initial state; i < -1: invalid)
            float e = (w == 0) ? em[0] : (w == 1) ? em[1] : (w == 2) ? em[2] : em[3];
            float a  = mrow[s] + __logf(y[s]) + e;        // transition path
            float bb = mrow[s] + __logf(serow[s]) + e;    // initial-state path (no transition)
            tv[s] = (i >= 0) ? a : ((i == -1) ? bb : NINF);
        }
        float mx = fmaxf(fmaxf(tv[0], tv[1]), fmaxf(tv[2], tv[3]));
        float sm = __expf(tv[0] - mx) + __expf(tv[1] - mx) +
                   __expf(tv[2] - mx) + __expf(tv[3] - mx);
        float alpha = mx + __logf(sm);

        // block max over k
        float wm = alpha;
#pragma unroll
        for (int o = 32; o; o >>= 1) wm = fmaxf(wm, __shfl_xor(wm, o, 64));
        if (lane == 0) redm[wv] = wm;
        __syncthreads();
        float mnew = fmaxf(fmaxf(redm[0], redm[1]), fmaxf(redm[2], redm[3]));

        float e = __expf(alpha - mnew);
        int slot = j & 3;                     // overwrites aged-out alpha[j-4]
        ebuf[slot * LDP + tid] = (_Float16)e;

        // block sum over k
        float wsum = e;
#pragma unroll
        for (int o = 32; o; o >>= 1) wsum += __shfl_xor(wsum, o, 64);
        if (lane == 0) reds[wv] = wsum;
        __syncthreads();
        if (tid == 0) {
            float snew = reds[0] + reds[1] + reds[2] + reds[3];
            mrow[slot] = mnew;
            serow[slot] = snew;
            ls[j + 1] = mnew + __logf(snew);
        }
        __syncthreads();
    }

    if (tid == 0) out[b] = ls[len_s];
}

extern "C" void kernel_launch(void* const* d_in, const int* in_sizes, int n_in,
                              void* d_out, int out_size, void* d_ws, size_t ws_size,
                              hipStream_t stream) {
    const float* logits   = (const float*)d_in[0];
    const float* T        = (const float*)d_in[1];
    const float* ham      = (const float*)d_in[2];
    const float* tag_mask = (const float*)d_in[3];
    const int*   text_mask= (const int*)d_in[4];
    float* out = (float*)d_out;

    _Float16* eT = (_Float16*)d_ws;   // CB*CK*CK f16 = 6.3 MB scratch
    int n = CB * CK * CK;
    prep_eT_kernel<<<(n + 255) / 256, 256, 0, stream>>>(T, tag_mask, eT, n);
    crf_scan_kernel<<<CB, 256, 0, stream>>>(logits, ham, eT, tag_mask, text_mask, out);
}

// Round 2
// 233.585 us; speedup vs baseline: 1.4524x; 1.4524x over previous
//
#include <hip/hip_runtime.h>
#include <hip/hip_bf16.h>
#include <type_traits>

typedef __attribute__((ext_vector_type(8))) _Float16 half8;
typedef __attribute__((ext_vector_type(4))) _Float16 half4;
typedef __attribute__((ext_vector_type(4))) float f32x4;

constexpr int CB = 48, CS = 128, CW = 4, CK = 256;
constexpr int LDP = 264;  // padded ebuf row stride (elements); 528 B = 33*16, keeps 16B alignment

// eT[b][k][kp] = exp(T[b][k][kp] * tag_mask[b][k][kp]) as f16, float4-vectorized
__global__ void prep_eT_kernel(const f32x4* __restrict__ T,
                               const f32x4* __restrict__ tm,
                               half4* __restrict__ eT, int n4) {
    int i = blockIdx.x * 256 + threadIdx.x;
    if (i < n4) {
        f32x4 t = T[i], m = tm[i];
        half4 o;
        o[0] = (_Float16)__expf(t[0] * m[0]);
        o[1] = (_Float16)__expf(t[1] * m[1]);
        o[2] = (_Float16)__expf(t[2] * m[2]);
        o[3] = (_Float16)__expf(t[3] * m[3]);
        eT[i] = o;
    }
}

__global__ __launch_bounds__(256, 1)
void crf_scan_kernel(const float* __restrict__ logits,
                     const float* __restrict__ ham,
                     const _Float16* __restrict__ eT,
                     const float* __restrict__ tag_mask,
                     const int* __restrict__ text_mask,
                     float* __restrict__ out) {
    const int b = blockIdx.x;
    const int tid = (int)threadIdx.x;
    const int wv = tid >> 6;
    const int lane = tid & 63;
    const int l16 = lane & 15;
    const int g4 = lane >> 4;

    // ebuf rows 0..3 = ring slots (slot of alpha_i = i&3); rows 4..15 permanently zero (pad M to 16)
    __shared__ alignas(16) _Float16 ebuf[16 * LDP];
    __shared__ alignas(16) float ylds[CK][4];   // y[k][slot], intra-wave transpose buffer
    __shared__ float red[4];
    __shared__ int len_s;

    for (int i = tid; i < 16 * LDP; i += 256) ebuf[i] = (_Float16)0.0f;
    if (tid == 0) len_s = 0;
    __syncthreads();
    // alpha_{-1} = zeros row: e = exp(0-0) = 1 in slot (-1)&3 = 3, M_{-1} = 0
    ebuf[3 * LDP + tid] = (_Float16)1.0f;
    if (tid < CS) atomicAdd(&len_s, text_mask[b * CS + tid]);

    const float tm0 = tag_mask[(size_t)b * CK * CK + tid];  // tag_mask[b,0,k]

    // persistent eT B-fragments (held in VGPRs for all 128 steps)
    half8 bfr[8][4];
    const _Float16* eTb = eT + (size_t)b * CK * CK;
#pragma unroll
    for (int c = 0; c < 8; ++c)
#pragma unroll
        for (int t = 0; t < 4; ++t) {
            int k = wv * 64 + t * 16 + l16;
            bfr[c][t] = *(const half8*)(eTb + (size_t)k * CK + c * 32 + g4 * 8);
        }
    half8 bones;  // ones column: y_ones[slot] = sum_kp ebuf[slot][kp]
#pragma unroll
    for (int q = 0; q < 8; ++q) bones[q] = (_Float16)1.0f;

    const float* lgb = logits + (size_t)b * CS * CW * CK;
    const float* hcb = ham    + (size_t)b * CS * CW * CK;

    // wave-uniform scan state (register-resident, identical on every thread)
    float mr[4] = {0.0f, 0.0f, 0.0f, 0.0f};  // mr[s] = normalizer M of alpha in slot s; mr[3]=M_{-1}=0
    float ls_prev = __logf(256.0f) - 2.0f;   // seeds delta=2 at j=0
    float out_r = __logf(256.0f);            // ls[0] (len==0 case)
    float e_last = 0.0f, M_last = 0.0f;

    __syncthreads();
    const int len = len_s;

    auto step = [&](int j, auto uc, auto firstc) {
        constexpr int u = uc.value;          // j & 3 (slot written this step)
        constexpr bool first = firstc.value; // j < 4 block
        // emission loads (global; consumed late in the step -> latency hidden)
        float lgv[4], hcv[4];
#pragma unroll
        for (int w = 0; w < 4; ++w) {
            int idx = j * (CW * CK) + w * CK + tid;
            lgv[w] = lgb[idx];
            hcv[w] = hcb[idx];
        }
        // A-fragments from ebuf (rows 4..15 zero)
        half8 af[8];
#pragma unroll
        for (int c = 0; c < 8; ++c)
            af[c] = *(const half8*)(ebuf + l16 * LDP + c * 32 + g4 * 8);

        f32x4 acc[4];
        f32x4 a1 = {0.0f, 0.0f, 0.0f, 0.0f};
#pragma unroll
        for (int t = 0; t < 4; ++t) acc[t] = (f32x4){0.0f, 0.0f, 0.0f, 0.0f};
#pragma unroll
        for (int c = 0; c < 8; ++c) {
#pragma unroll
            for (int t = 0; t < 4; ++t)
                acc[t] = __builtin_amdgcn_mfma_f32_16x16x32_f16(af[c], bfr[c][t], acc[t], 0, 0, 0);
            a1 = __builtin_amdgcn_mfma_f32_16x16x32_f16(af[c], bones, a1, 0, 0, 0);
        }

        // ls update (wave-uniform; lanes>=16 hold zero rows, so broadcast lane 0)
        constexpr int sp = (u + 3) & 3;  // slot of alpha_{j-1} (j=0: slot 3 = init row, sum=256)
        float sum_prev = __uint_as_float(
            __builtin_amdgcn_readfirstlane(__float_as_uint(a1[sp])));
        float lsj = mr[sp] + __logf(sum_prev);   // = reference ls[j]
        if (j == len) out_r = lsj;
        float delta = lsj - ls_prev;
        ls_prev = lsj;
        float Mj = lsj + delta;                  // predicted normalizer for alpha_j
        float C = mr[sp];

        // intra-wave transpose: D layout col=lane&15, row=reg (lanes 0..15) -> y[k][slot]
        if (lane < 16) {
#pragma unroll
            for (int t = 0; t < 4; ++t)
                *(f32x4*)(&ylds[wv * 64 + t * 16 + l16][0]) = acc[t];
        }
        f32x4 y = *(const f32x4*)(&ylds[tid][0]);  // same wave wrote this k-range

        // alpha = C + log(S), S = sum_w y[slot_w] * exp(mr[slot_w] + em_w - C)
        float S = 0.0f;
#pragma unroll
        for (int w = 0; w < 4; ++w) {
            constexpr_unroll:;
            const int sw = (u + 3 - w) & 3;  // slot of alpha_{j-1-w}; folds to literal
            float em = (lgv[w] + hcv[w]) * tm0;
            float yv = y[sw];
            if (first) {
                if (w == j) yv = 256.0f;      // initial-state path: no transition, alpha_{-1}=0 over K
                else if (w > j) yv = 0.0f;    // invalid (i < -1)
            }
            S = fmaf(yv, __expf(mr[sw] + em - C), S);
        }
        float e = S * __expf(C - Mj);            // = exp(alpha_j - Mj), fits f16
        ebuf[u * LDP + tid] = (_Float16)e;
        e_last = e;
        M_last = Mj;
        mr[u] = Mj;
        __syncthreads();                          // ebuf visible to all waves' A-frag loads
    };

#define IC(v) std::integral_constant<int, v>{}
#define BC(v) std::integral_constant<bool, v>{}
    step(0, IC(0), BC(true));
    step(1, IC(1), BC(true));
    step(2, IC(2), BC(true));
    step(3, IC(3), BC(true));
    for (int jj = 4; jj < CS; jj += 4) {
        step(jj + 0, IC(0), BC(false));
        step(jj + 1, IC(1), BC(false));
        step(jj + 2, IC(2), BC(false));
        step(jj + 3, IC(3), BC(false));
    }
#undef IC
#undef BC

    // ls[128] = M_127 + log(sum_k e_127) — one final reduction
    float s = e_last;
#pragma unroll
    for (int o = 32; o; o >>= 1) s += __shfl_xor(s, o, 64);
    if (lane == 0) red[wv] = s;
    __syncthreads();
    if (tid == 0) {
        float tot = red[0] + red[1] + red[2] + red[3];
        float ls_full = M_last + __logf(tot);
        if (len == CS) out_r = ls_full;
        out[b] = out_r;
    }
}

extern "C" void kernel_launch(void* const* d_in, const int* in_sizes, int n_in,
                              void* d_out, int out_size, void* d_ws, size_t ws_size,
                              hipStream_t stream) {
    const float* logits    = (const float*)d_in[0];
    const float* T         = (const float*)d_in[1];
    const float* ham       = (const float*)d_in[2];
    const float* tag_mask  = (const float*)d_in[3];
    const int*   text_mask = (const int*)d_in[4];
    float* out = (float*)d_out;

    _Float16* eT = (_Float16*)d_ws;  // CB*CK*CK f16 = 6.3 MB scratch
    int n4 = CB * CK * CK / 4;
    prep_eT_kernel<<<(n4 + 255) / 256, 256, 0, stream>>>(
        (const f32x4*)T, (const f32x4*)tag_mask, (half4*)eT, n4);
    crf_scan_kernel<<<CB, 256, 0, stream>>>(logits, ham, eT, tag_mask, text_mask, out);
}

// Round 3
// 198.727 us; speedup vs baseline: 1.7071x; 1.1754x over previous
//
#include <hip/hip_runtime.h>
#include <hip/hip_bf16.h>
#include <type_traits>

typedef __attribute__((ext_vector_type(8))) _Float16 half8;
typedef __attribute__((ext_vector_type(4))) _Float16 half4;
typedef __attribute__((ext_vector_type(2))) _Float16 half2;
typedef __attribute__((ext_vector_type(4))) float f32x4;

constexpr int CB = 48, CS = 128, CW = 4, CK = 256;
constexpr int LDP = 264;  // padded ebuf row stride (halves); 528 B keeps 16B alignment

// eT[b][k][kp] = exp(T[b][k][kp] * tag_mask[b][k][kp]) as f16, float4-vectorized
__global__ void prep_eT_kernel(const f32x4* __restrict__ T,
                               const f32x4* __restrict__ tm,
                               half4* __restrict__ eT, int n4) {
    int i = blockIdx.x * 256 + threadIdx.x;
    if (i < n4) {
        f32x4 t = T[i], m = tm[i];
        half4 o;
        o[0] = (_Float16)__expf(t[0] * m[0]);
        o[1] = (_Float16)__expf(t[1] * m[1]);
        o[2] = (_Float16)__expf(t[2] * m[2]);
        o[3] = (_Float16)__expf(t[3] * m[3]);
        eT[i] = o;
    }
}

__global__ __launch_bounds__(256, 1)
void crf_scan_kernel(const float* __restrict__ logits,
                     const float* __restrict__ ham,
                     const _Float16* __restrict__ eT,
                     const float* __restrict__ tag_mask,
                     const int* __restrict__ text_mask,
                     float* __restrict__ out) {
    const int b = blockIdx.x;
    const int tid = (int)threadIdx.x;
    const int wv = tid >> 6;
    const int lane = tid & 63;
    const int l16 = lane & 15;
    const int g4 = lane >> 4;

    // ebuf rows 0..3 = ring slots (slot of alpha_i = i&3); rows 4..15 permanently zero (pad M to 16)
    __shared__ alignas(16) _Float16 ebuf[16 * LDP];
    __shared__ alignas(16) float ylds[CK][4];   // y[k][slot], intra-wave transpose buffer
    __shared__ float red[4];
    __shared__ int len_s;

    for (int i = tid; i < 16 * LDP; i += 256) ebuf[i] = (_Float16)0.0f;
    if (tid == 0) len_s = 0;
    __syncthreads();
    // alpha_{-1} = zeros row: e = exp(0-0) = 1 in slot (-1)&3 = 3, M_{-1} = 0
    ebuf[3 * LDP + tid] = (_Float16)1.0f;
    if (tid < CS) atomicAdd(&len_s, text_mask[b * CS + tid]);

    const float tm0 = tag_mask[(size_t)b * CK * CK + tid];  // tag_mask[b,0,k]

    // persistent eT B-fragments (VGPR/AGPR-resident for all 128 steps)
    half8 bfr[8][4];
    const _Float16* eTb = eT + (size_t)b * CK * CK;
#pragma unroll
    for (int c = 0; c < 8; ++c)
#pragma unroll
        for (int t = 0; t < 4; ++t) {
            int k = wv * 64 + t * 16 + l16;
            bfr[c][t] = *(const half8*)(eTb + (size_t)k * CK + c * 32 + g4 * 8);
        }

    const float* lgb = logits + (size_t)b * CS * CW * CK;
    const float* hcb = ham    + (size_t)b * CS * CW * CK;

    // wave-uniform scan state (register-resident, identical on every thread)
    float mr[4] = {0.0f, 0.0f, 0.0f, 0.0f};  // mr[s] = normalizer M of alpha in slot s
    float ls_prev = __logf(256.0f) - 2.0f;   // seeds delta=2 at j=0
    float out_r = __logf(256.0f);            // ls[0] (len==0 case)
    float e_last = 0.0f, M_last = 0.0f;

    // emission prefetch for j=0 (consumed in step 0's epilogue)
    float em_cur[4];
#pragma unroll
    for (int w = 0; w < 4; ++w)
        em_cur[w] = (lgb[w * CK + tid] + hcb[w * CK + tid]) * tm0;

    __syncthreads();
    const int len = len_s;

    const half2 one2 = {(_Float16)1.0f, (_Float16)1.0f};

    auto step = [&](int j, auto uc, auto firstc) {
        constexpr int u = uc.value;          // j & 3 (slot written this step)
        constexpr bool first = firstc.value; // j < 4 block
        constexpr int sp = (u + 3) & 3;      // slot of alpha_{j-1}

        // A-fragments from ebuf (issue first; rows 4..15 zero)
        half8 af[8];
#pragma unroll
        for (int c = 0; c < 8; ++c)
            af[c] = *(const half8*)(ebuf + l16 * LDP + c * 32 + g4 * 8);

        // prefetch next step's emissions (consumed next step -> latency fully hidden)
        int jn = (j + 1 < CS) ? j + 1 : 0;   // wave-uniform clamp
        float lgn[4], hcn[4];
#pragma unroll
        for (int w = 0; w < 4; ++w) {
            int idx = jn * (CW * CK) + w * CK + tid;
            lgn[w] = lgb[idx];
            hcn[w] = hcb[idx];
        }

        // sum_prev = sum_kp ebuf[sp][kp], from A-frags via fdot2 (overlaps MFMA issue)
        float rs0 = 0.0f, rs1 = 0.0f;
#pragma unroll
        for (int c = 0; c < 8; ++c) {
#pragma unroll
            for (int p = 0; p < 4; p += 2) {
                half2 h0 = {af[c][2 * p], af[c][2 * p + 1]};
                half2 h1 = {af[c][2 * p + 2], af[c][2 * p + 3]};
                rs0 = __builtin_amdgcn_fdot2(h0, one2, rs0, false);
                rs1 = __builtin_amdgcn_fdot2(h1, one2, rs1, false);
            }
        }
        float rs = rs0 + rs1;                  // row-sum of row l16, kp chunk of this lane
        rs += __shfl_xor(rs, 16, 64);          // sum over g4
        rs += __shfl_xor(rs, 32, 64);
        float sum_prev = __shfl(rs, sp, 64);   // lanes l16==sp hold row sp's total

        float lsj = mr[sp] + __logf(sum_prev);   // reference ls[j]
        if (j == len) out_r = lsj;
        float delta = lsj - ls_prev;
        ls_prev = lsj;
        float Mj = lsj + delta;                  // predicted normalizer for alpha_j
        float C = mr[sp];

        // MFMA: y[slot][k] = sum_kp ebuf[slot][kp] * eT[k][kp]
        f32x4 acc[4];
#pragma unroll
        for (int t = 0; t < 4; ++t) acc[t] = (f32x4){0.0f, 0.0f, 0.0f, 0.0f};
#pragma unroll
        for (int c = 0; c < 8; ++c)
#pragma unroll
            for (int t = 0; t < 4; ++t)
                acc[t] = __builtin_amdgcn_mfma_f32_16x16x32_f16(af[c], bfr[c][t], acc[t], 0, 0, 0);

        // intra-wave transpose: D layout col=lane&15, row=reg (lanes 0..15) -> y[k][slot]
        if (lane < 16) {
#pragma unroll
            for (int t = 0; t < 4; ++t)
                *(f32x4*)(&ylds[wv * 64 + t * 16 + l16][0]) = acc[t];
        }
        f32x4 y = *(const f32x4*)(&ylds[tid][0]);  // same wave wrote this k-range

        // alpha = C + log(S), S = sum_w y[slot_w] * exp(mr[slot_w] + em_w - C)
        float S = 0.0f;
#pragma unroll
        for (int w = 0; w < 4; ++w) {
            const int sw = (u + 3 - w) & 3;  // slot of alpha_{j-1-w}; folds to literal
            float yv = y[sw];
            if (first) {
                if (w == j) yv = 256.0f;      // initial-state path (alpha_{-1}=0 over K)
                else if (w > j) yv = 0.0f;    // invalid (i < -1)
            }
            S = fmaf(yv, __expf(mr[sw] + em_cur[w] - C), S);
        }
        float e = S * __expf(C - Mj);            // = exp(alpha_j - Mj), fits f16
        ebuf[u * LDP + tid] = (_Float16)e;
        e_last = e;
        M_last = Mj;
        mr[u] = Mj;

        // rotate prefetched emissions into em_cur (vmcnt drained ~a full step after issue)
#pragma unroll
        for (int w = 0; w < 4; ++w)
            em_cur[w] = (lgn[w] + hcn[w]) * tm0;

        __syncthreads();                          // ebuf visible to all waves' A-frag loads
    };

#define IC(v) std::integral_constant<int, v>{}
#define BC(v) std::integral_constant<bool, v>{}
    step(0, IC(0), BC(true));
    step(1, IC(1), BC(true));
    step(2, IC(2), BC(true));
    step(3, IC(3), BC(true));
    for (int jj = 4; jj < CS; jj += 4) {
        step(jj + 0, IC(0), BC(false));
        step(jj + 1, IC(1), BC(false));
        step(jj + 2, IC(2), BC(false));
        step(jj + 3, IC(3), BC(false));
    }
#undef IC
#undef BC

    // ls[128] = M_127 + log(sum_k e_127) — one final reduction
    float s = e_last;
#pragma unroll
    for (int o = 32; o; o >>= 1) s += __shfl_xor(s, o, 64);
    if (lane == 0) red[wv] = s;
    __syncthreads();
    if (tid == 0) {
        float tot = red[0] + red[1] + red[2] + red[3];
        float ls_full = M_last + __logf(tot);
        if (len == CS) out_r = ls_full;
        out[b] = out_r;
    }
}

extern "C" void kernel_launch(void* const* d_in, const int* in_sizes, int n_in,
                              void* d_out, int out_size, void* d_ws, size_t ws_size,
                              hipStream_t stream) {
    const float* logits    = (const float*)d_in[0];
    const float* T         = (const float*)d_in[1];
    const float* ham       = (const float*)d_in[2];
    const float* tag_mask  = (const float*)d_in[3];
    const int*   text_mask = (const int*)d_in[4];
    float* out = (float*)d_out;

    _Float16* eT = (_Float16*)d_ws;  // CB*CK*CK f16 = 6.3 MB scratch
    int n4 = CB * CK * CK / 4;
    prep_eT_kernel<<<(n4 + 255) / 256, 256, 0, stream>>>(
        (const f32x4*)T, (const f32x4*)tag_mask, (half4*)eT, n4);
    crf_scan_kernel<<<CB, 256, 0, stream>>>(logits, ham, eT, tag_mask, text_mask, out);
}